// Round 1
// baseline (1447.779 us; speedup 1.0000x reference)
//
#include <hip/hip_runtime.h>

#define B_ 16
#define N_ 4096
#define CIN_ 64
#define COUT_ 128
#define K_ 16
#define M_ 1024

// ---------------------------------------------------------------------------
// FPS: one block per batch, 16 points per thread in registers.
// Exact-match discipline: _rn ops (no FMA contraction), ((dx^2+dy^2)+dz^2),
// argmax tie -> lowest index via u64 pack (dist_bits<<32 | (N-1-idx)).
// ---------------------------------------------------------------------------
__global__ __launch_bounds__(256) void fps_kernel(const float* __restrict__ pos,
                                                  int* __restrict__ fps_idx) {
  __shared__ float X[N_], Y[N_], Z[N_];
  __shared__ unsigned long long red[4];
  const int b = blockIdx.x;
  const int t = threadIdx.x;
  const float* pb = pos + (size_t)b * N_ * 3;
  for (int i = t; i < N_; i += 256) {
    X[i] = pb[i * 3 + 0];
    Y[i] = pb[i * 3 + 1];
    Z[i] = pb[i * 3 + 2];
  }
  __syncthreads();
  float px[16], py[16], pz[16], md[16];
#pragma unroll
  for (int i = 0; i < 16; ++i) {
    const int p = t + 256 * i;  // lane-consecutive point assignment
    px[i] = X[p]; py[i] = Y[p]; pz[i] = Z[p];
    md[i] = 1e10f;
  }
  if (t == 0) fps_idx[b * M_] = 0;
  int last = 0;
  for (int step = 1; step < M_; ++step) {
    const float lx = X[last], ly = Y[last], lz = Z[last];
    float bestd = -1.0f;
    int bestidx = 0;
#pragma unroll
    for (int i = 0; i < 16; ++i) {
      const float dx = __fsub_rn(px[i], lx);
      const float dy = __fsub_rn(py[i], ly);
      const float dz = __fsub_rn(pz[i], lz);
      const float d =
          __fadd_rn(__fadd_rn(__fmul_rn(dx, dx), __fmul_rn(dy, dy)), __fmul_rn(dz, dz));
      const float nd = fminf(md[i], d);
      md[i] = nd;
      if (nd > bestd) { bestd = nd; bestidx = t + 256 * i; }  // strict > keeps lowest idx
    }
    // md >= 0 always -> float bits are monotonic as unsigned
    unsigned long long pk = ((unsigned long long)__float_as_uint(bestd) << 32) |
                            (unsigned)(N_ - 1 - bestidx);
#pragma unroll
    for (int off = 1; off < 64; off <<= 1) {
      const unsigned long long o = __shfl_xor(pk, off, 64);
      if (o > pk) pk = o;
    }
    if ((t & 63) == 0) red[t >> 6] = pk;
    __syncthreads();
    const unsigned long long r01 = red[0] > red[1] ? red[0] : red[1];
    const unsigned long long r23 = red[2] > red[3] ? red[2] : red[3];
    const unsigned long long rr = r01 > r23 ? r01 : r23;
    last = N_ - 1 - (int)(unsigned)(rr & 0xFFFFFFFFu);
    if (t == 0) fps_idx[b * M_ + step] = last;
    __syncthreads();  // red[] reads done before next round's writes
  }
}

// ---------------------------------------------------------------------------
// h = features @ W + bias. Thread computes 4 outputs (float4), c-sequential fmaf.
// ---------------------------------------------------------------------------
__global__ __launch_bounds__(256) void linear_kernel(const float* __restrict__ f,
                                                     const float* __restrict__ W,
                                                     const float* __restrict__ bias,
                                                     float* __restrict__ h) {
  const int gid = blockIdx.x * 256 + threadIdx.x;
  const int r = gid >> 5;           // row in [0, B*N)
  const int o4 = (gid & 31) << 2;   // output channel base
  const float4* fr = (const float4*)(f + (size_t)r * CIN_);
  float4 acc = *(const float4*)(bias + o4);
#pragma unroll
  for (int c4 = 0; c4 < 16; ++c4) {
    const float4 fv = fr[c4];
    const float* wr = W + (size_t)(c4 * 4) * COUT_ + o4;
    const float4 w0 = *(const float4*)(wr);
    const float4 w1 = *(const float4*)(wr + COUT_);
    const float4 w2 = *(const float4*)(wr + 2 * COUT_);
    const float4 w3 = *(const float4*)(wr + 3 * COUT_);
    acc.x = fmaf(fv.x, w0.x, acc.x); acc.y = fmaf(fv.x, w0.y, acc.y);
    acc.z = fmaf(fv.x, w0.z, acc.z); acc.w = fmaf(fv.x, w0.w, acc.w);
    acc.x = fmaf(fv.y, w1.x, acc.x); acc.y = fmaf(fv.y, w1.y, acc.y);
    acc.z = fmaf(fv.y, w1.z, acc.z); acc.w = fmaf(fv.y, w1.w, acc.w);
    acc.x = fmaf(fv.z, w2.x, acc.x); acc.y = fmaf(fv.z, w2.y, acc.y);
    acc.z = fmaf(fv.z, w2.z, acc.z); acc.w = fmaf(fv.z, w2.w, acc.w);
    acc.x = fmaf(fv.w, w3.x, acc.x); acc.y = fmaf(fv.w, w3.y, acc.y);
    acc.z = fmaf(fv.w, w3.z, acc.z); acc.w = fmaf(fv.w, w3.w, acc.w);
  }
  *(float4*)(h + (size_t)r * COUT_ + o4) = acc;
}

// ---------------------------------------------------------------------------
// Per-channel sum / sumsq over all B*N rows. 256 blocks x 256 rows.
// ---------------------------------------------------------------------------
__global__ __launch_bounds__(256) void stats_kernel(const float* __restrict__ h,
                                                    float* __restrict__ stats) {
  const int o = threadIdx.x & 127;
  const int half = threadIdx.x >> 7;
  const int r0 = blockIdx.x * 256 + half * 128;
  float s = 0.f, ss = 0.f;
  for (int i = 0; i < 128; ++i) {
    const float v = h[(size_t)(r0 + i) * COUT_ + o];
    s += v;
    ss = fmaf(v, v, ss);
  }
  __shared__ float sh[2][128], shh[2][128];
  sh[half][o] = s; shh[half][o] = ss;
  __syncthreads();
  if (half == 0) {
    atomicAdd(&stats[o], s + sh[1][o]);
    atomicAdd(&stats[128 + o], ss + shh[1][o]);
  }
}

__global__ void finalize_kernel(float* __restrict__ stats,
                                const float* __restrict__ gamma,
                                const float* __restrict__ beta) {
  const int o = threadIdx.x;  // 128 threads
  const float inv = 1.0f / (float)(B_ * N_);
  const float mean = stats[o] * inv;
  const float var = stats[128 + o] * inv - mean * mean;
  const float r = 1.0f / sqrtf(var + 1e-5f);
  const float sc = gamma[o] * r;
  stats[256 + o] = sc;               // scale
  stats[384 + o] = beta[o] - mean * sc;  // shift
}

// ---------------------------------------------------------------------------
// kNN in feature space. Block = 512 threads, 64 queries, loop over 64-key tiles.
// d2 = (qq + ff) - 2*dot, matching the reference expansion. Exact (d, idx)
// lexicographic top-16 via packed u64 per-lane lists + 8-lane merge.
// ---------------------------------------------------------------------------
__device__ __forceinline__ unsigned mono32(float d) {
  unsigned u = __float_as_uint(d);
  return u ^ (unsigned)(((int)u >> 31) | 0x80000000);  // monotone float->u32
}

__global__ __launch_bounds__(512) void knn_kernel(const float* __restrict__ f,
                                                  const int* __restrict__ fps_idx,
                                                  int* __restrict__ nbr) {
  __shared__ __align__(16) float Qs[64 * 64];   // swizzled, stride 64
  __shared__ __align__(16) float Ks[64 * 64];   // swizzled, stride 64
  __shared__ __align__(16) float sd2[64 * 68];  // padded stride 68
  __shared__ float qq[64], ff[64];
  __shared__ int qid[64];
  const int b = blockIdx.x >> 4;
  const int qt = blockIdx.x & 15;
  const int t = threadIdx.x;
  const float* fb = f + (size_t)b * N_ * CIN_;
  if (t < 64) qid[t] = fps_idx[b * M_ + qt * 64 + t];
  __syncthreads();
  // stage queries (swizzle: physical col group pc = (c4 + row/4) & 15)
#pragma unroll
  for (int s = 0; s < 2; ++s) {
    const int id = t + 512 * s;
    const int row = id >> 4, c4 = id & 15;
    const int pc = (c4 + (row >> 2)) & 15;
    const float4 v = *(const float4*)(fb + (size_t)qid[row] * CIN_ + c4 * 4);
    *(float4*)(&Qs[row * 64 + pc * 4]) = v;
  }
  __syncthreads();
  if (t < 64) {
    float s = 0.f;
#pragma unroll
    for (int c4 = 0; c4 < 16; ++c4) {
      const int pc = (c4 + (t >> 2)) & 15;
      const float4 v = *(const float4*)(&Qs[t * 64 + pc * 4]);
      s = fmaf(v.x, v.x, s); s = fmaf(v.y, v.y, s);
      s = fmaf(v.z, v.z, s); s = fmaf(v.w, v.w, s);
    }
    qq[t] = s;
  }

  unsigned long long lst[16];
#pragma unroll
  for (int p = 0; p < 16; ++p) lst[p] = ~0ull;
  unsigned long long worst = ~0ull;
  int wpos = 0;

  const int tq = t >> 4;       // 0..31 : dot-phase query group (2 queries)
  const int tk = t & 15;       // 0..15 : dot-phase key group   (4 keys)
  const int q0 = tq * 2, k0 = tk * 4;
  const int sq = t >> 3;       // 0..63 : select-phase query
  const int ssub = t & 7;      // 0..7  : select-phase key subrange

  for (int kt = 0; kt < 64; ++kt) {
    // ---- stage key tile ----
#pragma unroll
    for (int s = 0; s < 2; ++s) {
      const int id = t + 512 * s;
      const int row = id >> 4, c4 = id & 15;
      const int pc = (c4 + (row >> 2)) & 15;
      const float4 v = *(const float4*)(fb + (size_t)(kt * 64 + row) * CIN_ + c4 * 4);
      *(float4*)(&Ks[row * 64 + pc * 4]) = v;
    }
    __syncthreads();
    if (t < 64) {
      float s = 0.f;
#pragma unroll
      for (int c4 = 0; c4 < 16; ++c4) {
        const int pc = (c4 + (t >> 2)) & 15;
        const float4 v = *(const float4*)(&Ks[t * 64 + pc * 4]);
        s = fmaf(v.x, v.x, s); s = fmaf(v.y, v.y, s);
        s = fmaf(v.z, v.z, s); s = fmaf(v.w, v.w, s);
      }
      ff[t] = s;
    }
    __syncthreads();
    // ---- dot phase: 2q x 4k register tile ----
    float acc[2][4];
#pragma unroll
    for (int i = 0; i < 2; ++i)
#pragma unroll
      for (int j = 0; j < 4; ++j) acc[i][j] = 0.f;
#pragma unroll
    for (int c4 = 0; c4 < 16; ++c4) {
      float4 qv[2], kv[4];
#pragma unroll
      for (int i = 0; i < 2; ++i) {
        const int row = q0 + i;
        const int pc = (c4 + (row >> 2)) & 15;
        qv[i] = *(const float4*)(&Qs[row * 64 + pc * 4]);
      }
#pragma unroll
      for (int j = 0; j < 4; ++j) {
        const int row = k0 + j;
        const int pc = (c4 + (row >> 2)) & 15;
        kv[j] = *(const float4*)(&Ks[row * 64 + pc * 4]);
      }
#pragma unroll
      for (int i = 0; i < 2; ++i)
#pragma unroll
        for (int j = 0; j < 4; ++j) {
          acc[i][j] = fmaf(qv[i].x, kv[j].x, acc[i][j]);
          acc[i][j] = fmaf(qv[i].y, kv[j].y, acc[i][j]);
          acc[i][j] = fmaf(qv[i].z, kv[j].z, acc[i][j]);
          acc[i][j] = fmaf(qv[i].w, kv[j].w, acc[i][j]);
        }
    }
#pragma unroll
    for (int i = 0; i < 2; ++i) {
      const float qv = qq[q0 + i];
      float4 o;
      o.x = __fsub_rn(__fadd_rn(qv, ff[k0 + 0]), 2.f * acc[i][0]);
      o.y = __fsub_rn(__fadd_rn(qv, ff[k0 + 1]), 2.f * acc[i][1]);
      o.z = __fsub_rn(__fadd_rn(qv, ff[k0 + 2]), 2.f * acc[i][2]);
      o.w = __fsub_rn(__fadd_rn(qv, ff[k0 + 3]), 2.f * acc[i][3]);
      *(float4*)(&sd2[(q0 + i) * 68 + k0]) = o;
    }
    __syncthreads();
    // ---- select phase: lane (sq, ssub) scans 8 keys of this tile ----
    const float4 v0 = *(const float4*)(&sd2[sq * 68 + ssub * 8]);
    const float4 v1 = *(const float4*)(&sd2[sq * 68 + ssub * 8 + 4]);
    const float dv[8] = {v0.x, v0.y, v0.z, v0.w, v1.x, v1.y, v1.z, v1.w};
#pragma unroll
    for (int jj = 0; jj < 8; ++jj) {
      const int key = kt * 64 + ssub * 8 + jj;
      const unsigned long long pk =
          ((unsigned long long)mono32(dv[jj]) << 32) | (unsigned)key;
      if (pk < worst) {  // exact lexicographic (d, idx): matches top_k ties
#pragma unroll
        for (int p = 0; p < 16; ++p)
          if (p == wpos) lst[p] = pk;
        worst = lst[0]; wpos = 0;
#pragma unroll
        for (int p = 1; p < 16; ++p)
          if (lst[p] > worst) { worst = lst[p]; wpos = p; }
      }
    }
    __syncthreads();  // sd2 reads done before next tile's dot writes
  }
  // ---- merge 8 per-lane lists per query -> global top-16 ----
  int* nb = nbr + (size_t)(b * M_ + qt * 64) * K_;
  for (int r = 0; r < K_; ++r) {
    unsigned long long mn = lst[0];
#pragma unroll
    for (int p = 1; p < 16; ++p)
      if (lst[p] < mn) mn = lst[p];
    unsigned long long m2 = mn;
#pragma unroll
    for (int off = 1; off < 8; off <<= 1) {
      const unsigned long long o = __shfl_xor(m2, off, 64);
      if (o < m2) m2 = o;
    }
    if (mn == m2) {  // unique keys -> exactly one owner lane
      bool done = false;
#pragma unroll
      for (int p = 0; p < 16; ++p)
        if (!done && lst[p] == m2) { lst[p] = ~0ull; done = true; }
    }
    if (ssub == 0) nb[sq * K_ + r] = (int)(unsigned)(m2 & 0xFFFFFFFFu);
  }
}

// ---------------------------------------------------------------------------
// Gather hn (= h*scale+shift, BN fused) at neighbors, maxpool over K.
// Block = 2 queries x 128 channels.
// ---------------------------------------------------------------------------
__global__ __launch_bounds__(256) void gather_kernel(const float* __restrict__ h,
                                                     const float* __restrict__ stats,
                                                     const int* __restrict__ nbr,
                                                     float* __restrict__ out) {
  const int g = blockIdx.x;
  const int q2 = threadIdx.x >> 7;
  const int o = threadIdx.x & 127;
  const int Q = g * 2 + q2;
  const int b = Q >> 10;
  __shared__ int nb[32];
  if (threadIdx.x < 32) nb[threadIdx.x] = nbr[(size_t)g * 32 + threadIdx.x];
  __syncthreads();
  const float sc = stats[256 + o];
  const float sh = stats[384 + o];
  float mx = -3.402823466e38f;
#pragma unroll
  for (int k = 0; k < K_; ++k) {
    const int n = nb[q2 * K_ + k];
    const float v = fmaf(h[((size_t)b * N_ + n) * COUT_ + o], sc, sh);
    mx = fmaxf(mx, v);
  }
  out[(size_t)Q * COUT_ + o] = mx;
}

// ---------------------------------------------------------------------------
// new_positions (gather at fps_idx) and new_batch (== Q>>10 by construction).
// ---------------------------------------------------------------------------
__global__ __launch_bounds__(256) void tail_kernel(const float* __restrict__ pos,
                                                   const int* __restrict__ fps_idx,
                                                   float* __restrict__ out,
                                                   int batch_as_i64) {
  const int gid = blockIdx.x * 256 + threadIdx.x;
  const int A = B_ * M_ * COUT_;
  const int P = B_ * M_ * 3;
  if (gid < P) {
    const int Q = gid / 3;
    const int c = gid - Q * 3;
    const int b = Q >> 10;
    const int idx = fps_idx[Q];
    out[A + gid] = pos[((size_t)b * N_ + idx) * 3 + c];
  } else {
    const int Q = gid - P;
    if (Q < B_ * M_) {
      const int b = Q >> 10;
      float* base = out + A + P;
      if (batch_as_i64)
        ((long long*)base)[Q] = (long long)b;
      else
        base[Q] = (float)b;
    }
  }
}

extern "C" void kernel_launch(void* const* d_in, const int* in_sizes, int n_in,
                              void* d_out, int out_size, void* d_ws, size_t ws_size,
                              hipStream_t stream) {
  const float* features = (const float*)d_in[0];
  const float* positions = (const float*)d_in[1];
  // d_in[2] (batch) not needed: new_batch[Q] == Q>>10 by construction
  const float* W = (const float*)d_in[3];
  const float* bias = (const float*)d_in[4];
  const float* gamma = (const float*)d_in[5];
  const float* beta = (const float*)d_in[6];
  float* out = (float*)d_out;
  unsigned char* ws = (unsigned char*)d_ws;

  int* fps_idx = (int*)ws;                                   // 64 KB
  float* h = (float*)(ws + 65536);                           // 33.5 MB
  float* stats = (float*)(ws + 65536 + (size_t)B_ * N_ * COUT_ * 4);  // 2 KB
  int* nbr = (int*)(ws + 65536 + (size_t)B_ * N_ * COUT_ * 4 + 2048); // 1 MB

  const int rem = out_size - (B_ * M_ * COUT_) - (B_ * M_ * 3);
  const int batch_as_i64 = (rem >= 2 * B_ * M_) ? 1 : 0;

  hipMemsetAsync(stats, 0, 256 * sizeof(float), stream);
  fps_kernel<<<B_, 256, 0, stream>>>(positions, fps_idx);
  linear_kernel<<<(B_ * N_ * 32) / 256, 256, 0, stream>>>(features, W, bias, h);
  stats_kernel<<<256, 256, 0, stream>>>(h, stats);
  finalize_kernel<<<1, 128, 0, stream>>>(stats, gamma, beta);
  knn_kernel<<<B_ * 16, 512, 0, stream>>>(features, fps_idx, nbr);
  gather_kernel<<<B_ * M_ / 2, 256, 0, stream>>>(h, stats, nbr, out);
  tail_kernel<<<256, 256, 0, stream>>>(positions, fps_idx, out, batch_as_i64);
}

// Round 2
// 1238.054 us; speedup vs baseline: 1.1694x; 1.1694x over previous
//
#include <hip/hip_runtime.h>

#define B_ 16
#define N_ 4096
#define CIN_ 64
#define COUT_ 128
#define K_ 16
#define M_ 1024

// ---------------------------------------------------------------------------
// FPS: one block per batch, 512 threads, 8 points per thread in registers.
// Exact-match discipline: _rn ops (no FMA contraction), ((dx^2+dy^2)+dz^2),
// argmax tie -> lowest index. Wave reduce via DPP (row_shr + row_bcast),
// cross-wave via double-buffered LDS tuples (ONE barrier per step).
// ---------------------------------------------------------------------------
#define DPPF(m, ctrl)                                                          \
  m = fmaxf(m, __int_as_float(__builtin_amdgcn_update_dpp(                     \
                  0, __float_as_int(m), ctrl, 0xF, 0xF, true)))
#define DPPI(e, ctrl)                                                          \
  e = max(e, __builtin_amdgcn_update_dpp(0, e, ctrl, 0xF, 0xF, true))

__global__ __launch_bounds__(512) void fps_kernel(const float* __restrict__ pos,
                                                  int* __restrict__ fps_idx) {
  __shared__ __align__(16) float4 P[N_];          // 64 KB
  __shared__ unsigned long long red[2][8];
  const int b = blockIdx.x;
  const int t = threadIdx.x;
  const float* pb = pos + (size_t)b * N_ * 3;
  for (int i = t; i < N_; i += 512)
    P[i] = make_float4(pb[i * 3], pb[i * 3 + 1], pb[i * 3 + 2], 0.f);
  __syncthreads();
  float px[8], py[8], pz[8], md[8];
#pragma unroll
  for (int i = 0; i < 8; ++i) {
    const float4 v = P[t + 512 * i];
    px[i] = v.x; py[i] = v.y; pz[i] = v.z;
    md[i] = 1e10f;
  }
  if (t == 0) fps_idx[b * M_] = 0;
  const int wv = t >> 6, ln = t & 63;
  const int e0 = 65535 - t;  // enc = 65535 - idx, idx = t + 512*i
  float4 lp = P[0];
  for (int step = 1; step < M_; ++step) {
    const float lx = lp.x, ly = lp.y, lz = lp.z;
    float bestd = -1.0f;
    int bi = 0;
#pragma unroll
    for (int i = 0; i < 8; ++i) {
      const float dx = __fsub_rn(px[i], lx);
      const float dy = __fsub_rn(py[i], ly);
      const float dz = __fsub_rn(pz[i], lz);
      const float d =
          __fadd_rn(__fadd_rn(__fmul_rn(dx, dx), __fmul_rn(dy, dy)), __fmul_rn(dz, dz));
      const float nd = fminf(md[i], d);
      md[i] = nd;
      if (nd > bestd) { bestd = nd; bi = i; }  // strict > keeps lowest idx
    }
    // intra-wave f32 max (distances >= 0, DPP bound_ctrl zeros are identity)
    float m = bestd;
    DPPF(m, 0x111); DPPF(m, 0x112); DPPF(m, 0x114); DPPF(m, 0x118);
    DPPF(m, 0x142); DPPF(m, 0x143);
    const float wm = __int_as_float(__builtin_amdgcn_readlane(__float_as_int(m), 63));
    // intra-wave lowest-index among maxima: max of (65535 - idx)
    int enc = (bestd == wm) ? (e0 - (bi << 9)) : 0;
    DPPI(enc, 0x111); DPPI(enc, 0x112); DPPI(enc, 0x114); DPPI(enc, 0x118);
    DPPI(enc, 0x142); DPPI(enc, 0x143);
    const int wenc = __builtin_amdgcn_readlane(enc, 63);
    if (ln == 0)
      red[step & 1][wv] =
          ((unsigned long long)__float_as_uint(wm) << 32) | (unsigned)wenc;
    __syncthreads();
    unsigned long long rr = red[step & 1][0];
#pragma unroll
    for (int w = 1; w < 8; ++w) {
      const unsigned long long o = red[step & 1][w];
      if (o > rr) rr = o;
    }
    const int last = 65535 - (int)(unsigned)(rr & 0xFFFFFFFFu);
    lp = P[last];
    if (t == 0) fps_idx[b * M_ + step] = last;
  }
}

// ---------------------------------------------------------------------------
// h = features @ W + bias. Thread computes 4 outputs (float4), c-sequential fmaf.
// ---------------------------------------------------------------------------
__global__ __launch_bounds__(256) void linear_kernel(const float* __restrict__ f,
                                                     const float* __restrict__ W,
                                                     const float* __restrict__ bias,
                                                     float* __restrict__ h) {
  const int gid = blockIdx.x * 256 + threadIdx.x;
  const int r = gid >> 5;
  const int o4 = (gid & 31) << 2;
  const float4* fr = (const float4*)(f + (size_t)r * CIN_);
  float4 acc = *(const float4*)(bias + o4);
#pragma unroll
  for (int c4 = 0; c4 < 16; ++c4) {
    const float4 fv = fr[c4];
    const float* wr = W + (size_t)(c4 * 4) * COUT_ + o4;
    const float4 w0 = *(const float4*)(wr);
    const float4 w1 = *(const float4*)(wr + COUT_);
    const float4 w2 = *(const float4*)(wr + 2 * COUT_);
    const float4 w3 = *(const float4*)(wr + 3 * COUT_);
    acc.x = fmaf(fv.x, w0.x, acc.x); acc.y = fmaf(fv.x, w0.y, acc.y);
    acc.z = fmaf(fv.x, w0.z, acc.z); acc.w = fmaf(fv.x, w0.w, acc.w);
    acc.x = fmaf(fv.y, w1.x, acc.x); acc.y = fmaf(fv.y, w1.y, acc.y);
    acc.z = fmaf(fv.y, w1.z, acc.z); acc.w = fmaf(fv.y, w1.w, acc.w);
    acc.x = fmaf(fv.z, w2.x, acc.x); acc.y = fmaf(fv.z, w2.y, acc.y);
    acc.z = fmaf(fv.z, w2.z, acc.z); acc.w = fmaf(fv.z, w2.w, acc.w);
    acc.x = fmaf(fv.w, w3.x, acc.x); acc.y = fmaf(fv.w, w3.y, acc.y);
    acc.z = fmaf(fv.w, w3.z, acc.z); acc.w = fmaf(fv.w, w3.w, acc.w);
  }
  *(float4*)(h + (size_t)r * COUT_ + o4) = acc;
}

// ---------------------------------------------------------------------------
// Per-channel sum / sumsq over all B*N rows.
// ---------------------------------------------------------------------------
__global__ __launch_bounds__(256) void stats_kernel(const float* __restrict__ h,
                                                    float* __restrict__ stats) {
  const int o = threadIdx.x & 127;
  const int half = threadIdx.x >> 7;
  const int r0 = blockIdx.x * 256 + half * 128;
  float s = 0.f, ss = 0.f;
  for (int i = 0; i < 128; ++i) {
    const float v = h[(size_t)(r0 + i) * COUT_ + o];
    s += v;
    ss = fmaf(v, v, ss);
  }
  __shared__ float sh[2][128], shh[2][128];
  sh[half][o] = s; shh[half][o] = ss;
  __syncthreads();
  if (half == 0) {
    atomicAdd(&stats[o], s + sh[1][o]);
    atomicAdd(&stats[128 + o], ss + shh[1][o]);
  }
}

__global__ void finalize_kernel(float* __restrict__ stats,
                                const float* __restrict__ gamma,
                                const float* __restrict__ beta) {
  const int o = threadIdx.x;  // 128
  const float inv = 1.0f / (float)(B_ * N_);
  const float mean = stats[o] * inv;
  const float var = stats[128 + o] * inv - mean * mean;
  const float r = 1.0f / sqrtf(var + 1e-5f);
  const float sc = gamma[o] * r;
  stats[256 + o] = sc;
  stats[384 + o] = beta[o] - mean * sc;
}

// ---------------------------------------------------------------------------
// kNN in feature space. 512 threads, 64 queries/block, 128-key tiles,
// 4q x 4k register tile per thread (8 LDS float4 reads per 64 fma).
// Exact (d, idx) lexicographic top-16 via packed u64 lists + 8-lane merge.
// ---------------------------------------------------------------------------
__device__ __forceinline__ unsigned mono32(float d) {
  unsigned u = __float_as_uint(d);
  return u ^ (unsigned)(((int)u >> 31) | 0x80000000);
}

__global__ __launch_bounds__(512) void knn_kernel(const float* __restrict__ f,
                                                  const int* __restrict__ fps_idx,
                                                  int* __restrict__ nbr) {
  __shared__ __align__(16) float Qs[64 * 64];    // 16 KB swizzled
  __shared__ __align__(16) float Ks[128 * 64];   // 32 KB swizzled
  __shared__ __align__(16) float sd2[64 * 132];  // 33 KB padded
  __shared__ float qq[64], ff[128];
  __shared__ int qid[64];
  const int b = blockIdx.x >> 4;
  const int qt = blockIdx.x & 15;
  const int t = threadIdx.x;
  const float* fb = f + (size_t)b * N_ * CIN_;
  if (t < 64) qid[t] = fps_idx[b * M_ + qt * 64 + t];
  __syncthreads();
#pragma unroll
  for (int s = 0; s < 2; ++s) {
    const int id = t + 512 * s;
    const int row = id >> 4, c4 = id & 15;
    const int pc = (c4 + (row >> 2)) & 15;
    const float4 v = *(const float4*)(fb + (size_t)qid[row] * CIN_ + c4 * 4);
    *(float4*)(&Qs[row * 64 + pc * 4]) = v;
  }
  __syncthreads();
  if (t < 64) {
    float s = 0.f;
#pragma unroll
    for (int c4 = 0; c4 < 16; ++c4) {
      const int pc = (c4 + (t >> 2)) & 15;
      const float4 v = *(const float4*)(&Qs[t * 64 + pc * 4]);
      s = fmaf(v.x, v.x, s); s = fmaf(v.y, v.y, s);
      s = fmaf(v.z, v.z, s); s = fmaf(v.w, v.w, s);
    }
    qq[t] = s;
  }

  unsigned long long lst[16];
#pragma unroll
  for (int p = 0; p < 16; ++p) lst[p] = ~0ull;
  unsigned long long worst = ~0ull;
  int wpos = 0;

  const int q0 = (t >> 5) * 4;   // dot-phase: 16 query groups of 4
  const int k0 = (t & 31) * 4;   // dot-phase: 32 key groups of 4
  const int sq = t >> 3;         // select-phase query 0..63
  const int ssub = t & 7;        // select-phase 16-key subrange

  for (int kt = 0; kt < 32; ++kt) {
    // ---- stage 128-key tile ----
#pragma unroll
    for (int s = 0; s < 4; ++s) {
      const int id = t + 512 * s;
      const int row = id >> 4, c4 = id & 15;
      const int pc = (c4 + (row >> 2)) & 15;
      const float4 v = *(const float4*)(fb + (size_t)(kt * 128 + row) * CIN_ + c4 * 4);
      *(float4*)(&Ks[row * 64 + pc * 4]) = v;
    }
    __syncthreads();
    if (t < 128) {
      float s = 0.f;
#pragma unroll
      for (int c4 = 0; c4 < 16; ++c4) {
        const int pc = (c4 + (t >> 2)) & 15;
        const float4 v = *(const float4*)(&Ks[t * 64 + pc * 4]);
        s = fmaf(v.x, v.x, s); s = fmaf(v.y, v.y, s);
        s = fmaf(v.z, v.z, s); s = fmaf(v.w, v.w, s);
      }
      ff[t] = s;
    }
    __syncthreads();
    // ---- dot phase: 4q x 4k ----
    float acc[4][4];
#pragma unroll
    for (int i = 0; i < 4; ++i)
#pragma unroll
      for (int j = 0; j < 4; ++j) acc[i][j] = 0.f;
#pragma unroll
    for (int c4 = 0; c4 < 16; ++c4) {
      float4 qv[4], kv[4];
#pragma unroll
      for (int i = 0; i < 4; ++i) {
        const int row = q0 + i;
        const int pc = (c4 + (row >> 2)) & 15;
        qv[i] = *(const float4*)(&Qs[row * 64 + pc * 4]);
      }
#pragma unroll
      for (int j = 0; j < 4; ++j) {
        const int row = k0 + j;
        const int pc = (c4 + (row >> 2)) & 15;
        kv[j] = *(const float4*)(&Ks[row * 64 + pc * 4]);
      }
#pragma unroll
      for (int i = 0; i < 4; ++i)
#pragma unroll
        for (int j = 0; j < 4; ++j) {
          acc[i][j] = fmaf(qv[i].x, kv[j].x, acc[i][j]);
          acc[i][j] = fmaf(qv[i].y, kv[j].y, acc[i][j]);
          acc[i][j] = fmaf(qv[i].z, kv[j].z, acc[i][j]);
          acc[i][j] = fmaf(qv[i].w, kv[j].w, acc[i][j]);
        }
    }
#pragma unroll
    for (int i = 0; i < 4; ++i) {
      const float qv = qq[q0 + i];
      float4 o;
      o.x = __fsub_rn(__fadd_rn(qv, ff[k0 + 0]), 2.f * acc[i][0]);
      o.y = __fsub_rn(__fadd_rn(qv, ff[k0 + 1]), 2.f * acc[i][1]);
      o.z = __fsub_rn(__fadd_rn(qv, ff[k0 + 2]), 2.f * acc[i][2]);
      o.w = __fsub_rn(__fadd_rn(qv, ff[k0 + 3]), 2.f * acc[i][3]);
      *(float4*)(&sd2[(q0 + i) * 132 + k0]) = o;
    }
    __syncthreads();
    // ---- select phase: lane (sq, ssub) scans 16 keys ----
#pragma unroll
    for (int g = 0; g < 4; ++g) {
      const float4 v = *(const float4*)(&sd2[sq * 132 + ssub * 16 + g * 4]);
      const float dv[4] = {v.x, v.y, v.z, v.w};
#pragma unroll
      for (int jj = 0; jj < 4; ++jj) {
        const int key = kt * 128 + ssub * 16 + g * 4 + jj;
        const unsigned long long pk =
            ((unsigned long long)mono32(dv[jj]) << 32) | (unsigned)key;
        if (pk < worst) {
#pragma unroll
          for (int p = 0; p < 16; ++p)
            if (p == wpos) lst[p] = pk;
          worst = lst[0]; wpos = 0;
#pragma unroll
          for (int p = 1; p < 16; ++p)
            if (lst[p] > worst) { worst = lst[p]; wpos = p; }
        }
      }
    }
    __syncthreads();
  }
  // ---- merge 8 per-lane lists per query ----
  int* nb = nbr + (size_t)(b * M_ + qt * 64) * K_;
  for (int r = 0; r < K_; ++r) {
    unsigned long long mn = lst[0];
#pragma unroll
    for (int p = 1; p < 16; ++p)
      if (lst[p] < mn) mn = lst[p];
    unsigned long long m2 = mn;
#pragma unroll
    for (int off = 1; off < 8; off <<= 1) {
      const unsigned long long o = __shfl_xor(m2, off, 64);
      if (o < m2) m2 = o;
    }
    if (mn == m2) {
      bool done = false;
#pragma unroll
      for (int p = 0; p < 16; ++p)
        if (!done && lst[p] == m2) { lst[p] = ~0ull; done = true; }
    }
    if (ssub == 0) nb[sq * K_ + r] = (int)(unsigned)(m2 & 0xFFFFFFFFu);
  }
}

// ---------------------------------------------------------------------------
// Gather h*scale+shift at neighbors, maxpool over K.
// ---------------------------------------------------------------------------
__global__ __launch_bounds__(256) void gather_kernel(const float* __restrict__ h,
                                                     const float* __restrict__ stats,
                                                     const int* __restrict__ nbr,
                                                     float* __restrict__ out) {
  const int g = blockIdx.x;
  const int q2 = threadIdx.x >> 7;
  const int o = threadIdx.x & 127;
  const int Q = g * 2 + q2;
  const int b = Q >> 10;
  __shared__ int nb[32];
  if (threadIdx.x < 32) nb[threadIdx.x] = nbr[(size_t)g * 32 + threadIdx.x];
  __syncthreads();
  const float sc = stats[256 + o];
  const float sh = stats[384 + o];
  float mx = -3.402823466e38f;
#pragma unroll
  for (int k = 0; k < K_; ++k) {
    const int n = nb[q2 * K_ + k];
    const float v = fmaf(h[((size_t)b * N_ + n) * COUT_ + o], sc, sh);
    mx = fmaxf(mx, v);
  }
  out[(size_t)Q * COUT_ + o] = mx;
}

__global__ __launch_bounds__(256) void tail_kernel(const float* __restrict__ pos,
                                                   const int* __restrict__ fps_idx,
                                                   float* __restrict__ out,
                                                   int batch_as_i64) {
  const int gid = blockIdx.x * 256 + threadIdx.x;
  const int A = B_ * M_ * COUT_;
  const int P = B_ * M_ * 3;
  if (gid < P) {
    const int Q = gid / 3;
    const int c = gid - Q * 3;
    const int b = Q >> 10;
    const int idx = fps_idx[Q];
    out[A + gid] = pos[((size_t)b * N_ + idx) * 3 + c];
  } else {
    const int Q = gid - P;
    if (Q < B_ * M_) {
      const int b = Q >> 10;
      float* base = out + A + P;
      if (batch_as_i64)
        ((long long*)base)[Q] = (long long)b;
      else
        base[Q] = (float)b;
    }
  }
}

extern "C" void kernel_launch(void* const* d_in, const int* in_sizes, int n_in,
                              void* d_out, int out_size, void* d_ws, size_t ws_size,
                              hipStream_t stream) {
  const float* features = (const float*)d_in[0];
  const float* positions = (const float*)d_in[1];
  const float* W = (const float*)d_in[3];
  const float* bias = (const float*)d_in[4];
  const float* gamma = (const float*)d_in[5];
  const float* beta = (const float*)d_in[6];
  float* out = (float*)d_out;
  unsigned char* ws = (unsigned char*)d_ws;

  int* fps_idx = (int*)ws;
  float* h = (float*)(ws + 65536);
  float* stats = (float*)(ws + 65536 + (size_t)B_ * N_ * COUT_ * 4);
  int* nbr = (int*)(ws + 65536 + (size_t)B_ * N_ * COUT_ * 4 + 2048);

  const int rem = out_size - (B_ * M_ * COUT_) - (B_ * M_ * 3);
  const int batch_as_i64 = (rem >= 2 * B_ * M_) ? 1 : 0;

  hipMemsetAsync(stats, 0, 256 * sizeof(float), stream);
  fps_kernel<<<B_, 512, 0, stream>>>(positions, fps_idx);
  linear_kernel<<<(B_ * N_ * 32) / 256, 256, 0, stream>>>(features, W, bias, h);
  stats_kernel<<<256, 256, 0, stream>>>(h, stats);
  finalize_kernel<<<1, 128, 0, stream>>>(stats, gamma, beta);
  knn_kernel<<<B_ * 16, 512, 0, stream>>>(features, fps_idx, nbr);
  gather_kernel<<<B_ * M_ / 2, 256, 0, stream>>>(h, stats, nbr, out);
  tail_kernel<<<256, 256, 0, stream>>>(positions, fps_idx, out, batch_as_i64);
}

// Round 3
// 1164.161 us; speedup vs baseline: 1.2436x; 1.0635x over previous
//
#include <hip/hip_runtime.h>

#define B_ 16
#define N_ 4096
#define CIN_ 64
#define COUT_ 128
#define K_ 16
#define M_ 1024

typedef float f32x2 __attribute__((ext_vector_type(2)));

// ---------------------------------------------------------------------------
// FPS: one block per batch, 256 threads (4 waves = 1/SIMD), 16 points per
// thread as 8 packed float2 (v_pk_* VOP3P). Exact-match discipline:
// contract(off) + explicit ((dx^2+dy^2)+dz^2) order, argmax tie -> lowest
// index (ascending scan with strict >). Wave reduce via DPP, cross-wave via
// 4-slot double-buffered LDS u64 tuples (ONE barrier per step).
// ---------------------------------------------------------------------------
#define DPPF(m, ctrl)                                                          \
  m = fmaxf(m, __int_as_float(__builtin_amdgcn_update_dpp(                     \
                  0, __float_as_int(m), ctrl, 0xF, 0xF, true)))
#define DPPI(e, ctrl)                                                          \
  e = max(e, __builtin_amdgcn_update_dpp(0, e, ctrl, 0xF, 0xF, true))

__global__ __launch_bounds__(256) void fps_kernel(const float* __restrict__ pos,
                                                  int* __restrict__ fps_idx) {
  __shared__ __align__(16) float4 P[N_];  // 64 KB
  __shared__ __align__(16) unsigned long long red[2][4];
  const int b = blockIdx.x;
  const int t = threadIdx.x;
  const float* pb = pos + (size_t)b * N_ * 3;
  for (int i = t; i < N_; i += 256)
    P[i] = make_float4(pb[i * 3], pb[i * 3 + 1], pb[i * 3 + 2], 0.f);
  __syncthreads();
  f32x2 px[8], py[8], pz[8], md[8];
#pragma unroll
  for (int j = 0; j < 8; ++j) {
    const float4 lo = P[t + 512 * j];        // idx = t + 256*(2j)
    const float4 hi = P[t + 512 * j + 256];  // idx = t + 256*(2j+1)
    px[j] = (f32x2){lo.x, hi.x};
    py[j] = (f32x2){lo.y, hi.y};
    pz[j] = (f32x2){lo.z, hi.z};
    md[j] = (f32x2){1e10f, 1e10f};
  }
  if (t == 0) fps_idx[b * M_] = 0;
  const int wv = t >> 6, ln = t & 63;
  const int e0 = 65535 - t;  // enc = 65535 - idx; idx = t + 256*(2j+h)
  float4 lp = P[0];
  for (int step = 1; step < M_; ++step) {
    const f32x2 lx = {lp.x, lp.x}, ly = {lp.y, lp.y}, lz = {lp.z, lp.z};
    float bestd = -1.0f;
    int be = 0;
    {
#pragma clang fp contract(off)
#pragma unroll
      for (int j = 0; j < 8; ++j) {
        const f32x2 dx = px[j] - lx;
        const f32x2 dy = py[j] - ly;
        const f32x2 dz = pz[j] - lz;
        const f32x2 s1 = dx * dx;
        const f32x2 s2 = dy * dy;
        const f32x2 s3 = dz * dz;
        const f32x2 d = (s1 + s2) + s3;  // exact reference order, no fma
        f32x2 nd;
        nd.x = fminf(md[j].x, d.x);
        nd.y = fminf(md[j].y, d.y);
        md[j] = nd;
        if (nd.x > bestd) { bestd = nd.x; be = e0 - (j << 9); }
        if (nd.y > bestd) { bestd = nd.y; be = e0 - (j << 9) - 256; }
      }
    }
    // intra-wave f32 max (distances >= 0; DPP bound_ctrl zeros are identity)
    float m = bestd;
    DPPF(m, 0x111); DPPF(m, 0x112); DPPF(m, 0x114); DPPF(m, 0x118);
    DPPF(m, 0x142); DPPF(m, 0x143);
    const float wm = __int_as_float(__builtin_amdgcn_readlane(__float_as_int(m), 63));
    // intra-wave lowest index among maxima: max of enc
    int enc = (bestd == wm) ? be : 0;
    DPPI(enc, 0x111); DPPI(enc, 0x112); DPPI(enc, 0x114); DPPI(enc, 0x118);
    DPPI(enc, 0x142); DPPI(enc, 0x143);
    const int wenc = __builtin_amdgcn_readlane(enc, 63);
    if (ln == 0)
      red[step & 1][wv] =
          ((unsigned long long)__float_as_uint(wm) << 32) | (unsigned)wenc;
    __syncthreads();
    const ulonglong2 r01 = *(const ulonglong2*)&red[step & 1][0];
    const ulonglong2 r23 = *(const ulonglong2*)&red[step & 1][2];
    unsigned long long rr = r01.x > r01.y ? r01.x : r01.y;
    const unsigned long long rb = r23.x > r23.y ? r23.x : r23.y;
    if (rb > rr) rr = rb;
    const int last = 65535 - (int)(unsigned)(rr & 0xFFFFFFFFu);
    lp = P[last];
    if (t == 0) fps_idx[b * M_ + step] = last;
  }
}

// ---------------------------------------------------------------------------
// h = features @ W + bias. Thread computes 4 outputs (float4), c-sequential fmaf.
// ---------------------------------------------------------------------------
__global__ __launch_bounds__(256) void linear_kernel(const float* __restrict__ f,
                                                     const float* __restrict__ W,
                                                     const float* __restrict__ bias,
                                                     float* __restrict__ h) {
  const int gid = blockIdx.x * 256 + threadIdx.x;
  const int r = gid >> 5;
  const int o4 = (gid & 31) << 2;
  const float4* fr = (const float4*)(f + (size_t)r * CIN_);
  float4 acc = *(const float4*)(bias + o4);
#pragma unroll
  for (int c4 = 0; c4 < 16; ++c4) {
    const float4 fv = fr[c4];
    const float* wr = W + (size_t)(c4 * 4) * COUT_ + o4;
    const float4 w0 = *(const float4*)(wr);
    const float4 w1 = *(const float4*)(wr + COUT_);
    const float4 w2 = *(const float4*)(wr + 2 * COUT_);
    const float4 w3 = *(const float4*)(wr + 3 * COUT_);
    acc.x = fmaf(fv.x, w0.x, acc.x); acc.y = fmaf(fv.x, w0.y, acc.y);
    acc.z = fmaf(fv.x, w0.z, acc.z); acc.w = fmaf(fv.x, w0.w, acc.w);
    acc.x = fmaf(fv.y, w1.x, acc.x); acc.y = fmaf(fv.y, w1.y, acc.y);
    acc.z = fmaf(fv.y, w1.z, acc.z); acc.w = fmaf(fv.y, w1.w, acc.w);
    acc.x = fmaf(fv.z, w2.x, acc.x); acc.y = fmaf(fv.z, w2.y, acc.y);
    acc.z = fmaf(fv.z, w2.z, acc.z); acc.w = fmaf(fv.z, w2.w, acc.w);
    acc.x = fmaf(fv.w, w3.x, acc.x); acc.y = fmaf(fv.w, w3.y, acc.y);
    acc.z = fmaf(fv.w, w3.z, acc.z); acc.w = fmaf(fv.w, w3.w, acc.w);
  }
  *(float4*)(h + (size_t)r * COUT_ + o4) = acc;
}

// ---------------------------------------------------------------------------
// Per-channel sum / sumsq over all B*N rows.
// ---------------------------------------------------------------------------
__global__ __launch_bounds__(256) void stats_kernel(const float* __restrict__ h,
                                                    float* __restrict__ stats) {
  const int o = threadIdx.x & 127;
  const int half = threadIdx.x >> 7;
  const int r0 = blockIdx.x * 256 + half * 128;
  float s = 0.f, ss = 0.f;
  for (int i = 0; i < 128; ++i) {
    const float v = h[(size_t)(r0 + i) * COUT_ + o];
    s += v;
    ss = fmaf(v, v, ss);
  }
  __shared__ float sh[2][128], shh[2][128];
  sh[half][o] = s; shh[half][o] = ss;
  __syncthreads();
  if (half == 0) {
    atomicAdd(&stats[o], s + sh[1][o]);
    atomicAdd(&stats[128 + o], ss + shh[1][o]);
  }
}

__global__ void finalize_kernel(float* __restrict__ stats,
                                const float* __restrict__ gamma,
                                const float* __restrict__ beta) {
  const int o = threadIdx.x;  // 128
  const float inv = 1.0f / (float)(B_ * N_);
  const float mean = stats[o] * inv;
  const float var = stats[128 + o] * inv - mean * mean;
  const float r = 1.0f / sqrtf(var + 1e-5f);
  const float sc = gamma[o] * r;
  stats[256 + o] = sc;
  stats[384 + o] = beta[o] - mean * sc;
}

// ---------------------------------------------------------------------------
// kNN in feature space. 512 threads, 64 queries/block, 128-key tiles,
// 4q x 4k register tile. Exact (d, idx) lexicographic top-16.
// ---------------------------------------------------------------------------
__device__ __forceinline__ unsigned mono32(float d) {
  unsigned u = __float_as_uint(d);
  return u ^ (unsigned)(((int)u >> 31) | 0x80000000);
}

__global__ __launch_bounds__(512) void knn_kernel(const float* __restrict__ f,
                                                  const int* __restrict__ fps_idx,
                                                  int* __restrict__ nbr) {
  __shared__ __align__(16) float Qs[64 * 64];
  __shared__ __align__(16) float Ks[128 * 64];
  __shared__ __align__(16) float sd2[64 * 132];
  __shared__ float qq[64], ff[128];
  __shared__ int qid[64];
  const int b = blockIdx.x >> 4;
  const int qt = blockIdx.x & 15;
  const int t = threadIdx.x;
  const float* fb = f + (size_t)b * N_ * CIN_;
  if (t < 64) qid[t] = fps_idx[b * M_ + qt * 64 + t];
  __syncthreads();
#pragma unroll
  for (int s = 0; s < 2; ++s) {
    const int id = t + 512 * s;
    const int row = id >> 4, c4 = id & 15;
    const int pc = (c4 + (row >> 2)) & 15;
    const float4 v = *(const float4*)(fb + (size_t)qid[row] * CIN_ + c4 * 4);
    *(float4*)(&Qs[row * 64 + pc * 4]) = v;
  }
  __syncthreads();
  if (t < 64) {
    float s = 0.f;
#pragma unroll
    for (int c4 = 0; c4 < 16; ++c4) {
      const int pc = (c4 + (t >> 2)) & 15;
      const float4 v = *(const float4*)(&Qs[t * 64 + pc * 4]);
      s = fmaf(v.x, v.x, s); s = fmaf(v.y, v.y, s);
      s = fmaf(v.z, v.z, s); s = fmaf(v.w, v.w, s);
    }
    qq[t] = s;
  }

  unsigned long long lst[16];
#pragma unroll
  for (int p = 0; p < 16; ++p) lst[p] = ~0ull;
  unsigned long long worst = ~0ull;
  int wpos = 0;

  const int q0 = (t >> 5) * 4;
  const int k0 = (t & 31) * 4;
  const int sq = t >> 3;
  const int ssub = t & 7;

  for (int kt = 0; kt < 32; ++kt) {
#pragma unroll
    for (int s = 0; s < 4; ++s) {
      const int id = t + 512 * s;
      const int row = id >> 4, c4 = id & 15;
      const int pc = (c4 + (row >> 2)) & 15;
      const float4 v = *(const float4*)(fb + (size_t)(kt * 128 + row) * CIN_ + c4 * 4);
      *(float4*)(&Ks[row * 64 + pc * 4]) = v;
    }
    __syncthreads();
    if (t < 128) {
      float s = 0.f;
#pragma unroll
      for (int c4 = 0; c4 < 16; ++c4) {
        const int pc = (c4 + (t >> 2)) & 15;
        const float4 v = *(const float4*)(&Ks[t * 64 + pc * 4]);
        s = fmaf(v.x, v.x, s); s = fmaf(v.y, v.y, s);
        s = fmaf(v.z, v.z, s); s = fmaf(v.w, v.w, s);
      }
      ff[t] = s;
    }
    __syncthreads();
    float acc[4][4];
#pragma unroll
    for (int i = 0; i < 4; ++i)
#pragma unroll
      for (int j = 0; j < 4; ++j) acc[i][j] = 0.f;
#pragma unroll
    for (int c4 = 0; c4 < 16; ++c4) {
      float4 qv[4], kv[4];
#pragma unroll
      for (int i = 0; i < 4; ++i) {
        const int row = q0 + i;
        const int pc = (c4 + (row >> 2)) & 15;
        qv[i] = *(const float4*)(&Qs[row * 64 + pc * 4]);
      }
#pragma unroll
      for (int j = 0; j < 4; ++j) {
        const int row = k0 + j;
        const int pc = (c4 + (row >> 2)) & 15;
        kv[j] = *(const float4*)(&Ks[row * 64 + pc * 4]);
      }
#pragma unroll
      for (int i = 0; i < 4; ++i)
#pragma unroll
        for (int j = 0; j < 4; ++j) {
          acc[i][j] = fmaf(qv[i].x, kv[j].x, acc[i][j]);
          acc[i][j] = fmaf(qv[i].y, kv[j].y, acc[i][j]);
          acc[i][j] = fmaf(qv[i].z, kv[j].z, acc[i][j]);
          acc[i][j] = fmaf(qv[i].w, kv[j].w, acc[i][j]);
        }
    }
#pragma unroll
    for (int i = 0; i < 4; ++i) {
      const float qv = qq[q0 + i];
      float4 o;
      o.x = __fsub_rn(__fadd_rn(qv, ff[k0 + 0]), 2.f * acc[i][0]);
      o.y = __fsub_rn(__fadd_rn(qv, ff[k0 + 1]), 2.f * acc[i][1]);
      o.z = __fsub_rn(__fadd_rn(qv, ff[k0 + 2]), 2.f * acc[i][2]);
      o.w = __fsub_rn(__fadd_rn(qv, ff[k0 + 3]), 2.f * acc[i][3]);
      *(float4*)(&sd2[(q0 + i) * 132 + k0]) = o;
    }
    __syncthreads();
#pragma unroll
    for (int g = 0; g < 4; ++g) {
      const float4 v = *(const float4*)(&sd2[sq * 132 + ssub * 16 + g * 4]);
      const float dv[4] = {v.x, v.y, v.z, v.w};
#pragma unroll
      for (int jj = 0; jj < 4; ++jj) {
        const int key = kt * 128 + ssub * 16 + g * 4 + jj;
        const unsigned long long pk =
            ((unsigned long long)mono32(dv[jj]) << 32) | (unsigned)key;
        if (pk < worst) {
#pragma unroll
          for (int p = 0; p < 16; ++p)
            if (p == wpos) lst[p] = pk;
          worst = lst[0]; wpos = 0;
#pragma unroll
          for (int p = 1; p < 16; ++p)
            if (lst[p] > worst) { worst = lst[p]; wpos = p; }
        }
      }
    }
    __syncthreads();
  }
  int* nb = nbr + (size_t)(b * M_ + qt * 64) * K_;
  for (int r = 0; r < K_; ++r) {
    unsigned long long mn = lst[0];
#pragma unroll
    for (int p = 1; p < 16; ++p)
      if (lst[p] < mn) mn = lst[p];
    unsigned long long m2 = mn;
#pragma unroll
    for (int off = 1; off < 8; off <<= 1) {
      const unsigned long long o = __shfl_xor(m2, off, 64);
      if (o < m2) m2 = o;
    }
    if (mn == m2) {
      bool done = false;
#pragma unroll
      for (int p = 0; p < 16; ++p)
        if (!done && lst[p] == m2) { lst[p] = ~0ull; done = true; }
    }
    if (ssub == 0) nb[sq * K_ + r] = (int)(unsigned)(m2 & 0xFFFFFFFFu);
  }
}

// ---------------------------------------------------------------------------
// Gather h*scale+shift at neighbors, maxpool over K.
// ---------------------------------------------------------------------------
__global__ __launch_bounds__(256) void gather_kernel(const float* __restrict__ h,
                                                     const float* __restrict__ stats,
                                                     const int* __restrict__ nbr,
                                                     float* __restrict__ out) {
  const int g = blockIdx.x;
  const int q2 = threadIdx.x >> 7;
  const int o = threadIdx.x & 127;
  const int Q = g * 2 + q2;
  const int b = Q >> 10;
  __shared__ int nb[32];
  if (threadIdx.x < 32) nb[threadIdx.x] = nbr[(size_t)g * 32 + threadIdx.x];
  __syncthreads();
  const float sc = stats[256 + o];
  const float sh = stats[384 + o];
  float mx = -3.402823466e38f;
#pragma unroll
  for (int k = 0; k < K_; ++k) {
    const int n = nb[q2 * K_ + k];
    const float v = fmaf(h[((size_t)b * N_ + n) * COUT_ + o], sc, sh);
    mx = fmaxf(mx, v);
  }
  out[(size_t)Q * COUT_ + o] = mx;
}

__global__ __launch_bounds__(256) void tail_kernel(const float* __restrict__ pos,
                                                   const int* __restrict__ fps_idx,
                                                   float* __restrict__ out,
                                                   int batch_as_i64) {
  const int gid = blockIdx.x * 256 + threadIdx.x;
  const int A = B_ * M_ * COUT_;
  const int P = B_ * M_ * 3;
  if (gid < P) {
    const int Q = gid / 3;
    const int c = gid - Q * 3;
    const int b = Q >> 10;
    const int idx = fps_idx[Q];
    out[A + gid] = pos[((size_t)b * N_ + idx) * 3 + c];
  } else {
    const int Q = gid - P;
    if (Q < B_ * M_) {
      const int b = Q >> 10;
      float* base = out + A + P;
      if (batch_as_i64)
        ((long long*)base)[Q] = (long long)b;
      else
        base[Q] = (float)b;
    }
  }
}

extern "C" void kernel_launch(void* const* d_in, const int* in_sizes, int n_in,
                              void* d_out, int out_size, void* d_ws, size_t ws_size,
                              hipStream_t stream) {
  const float* features = (const float*)d_in[0];
  const float* positions = (const float*)d_in[1];
  const float* W = (const float*)d_in[3];
  const float* bias = (const float*)d_in[4];
  const float* gamma = (const float*)d_in[5];
  const float* beta = (const float*)d_in[6];
  float* out = (float*)d_out;
  unsigned char* ws = (unsigned char*)d_ws;

  int* fps_idx = (int*)ws;
  float* h = (float*)(ws + 65536);
  float* stats = (float*)(ws + 65536 + (size_t)B_ * N_ * COUT_ * 4);
  int* nbr = (int*)(ws + 65536 + (size_t)B_ * N_ * COUT_ * 4 + 2048);

  const int rem = out_size - (B_ * M_ * COUT_) - (B_ * M_ * 3);
  const int batch_as_i64 = (rem >= 2 * B_ * M_) ? 1 : 0;

  hipMemsetAsync(stats, 0, 256 * sizeof(float), stream);
  fps_kernel<<<B_, 256, 0, stream>>>(positions, fps_idx);
  linear_kernel<<<(B_ * N_ * 32) / 256, 256, 0, stream>>>(features, W, bias, h);
  stats_kernel<<<256, 256, 0, stream>>>(h, stats);
  finalize_kernel<<<1, 128, 0, stream>>>(stats, gamma, beta);
  knn_kernel<<<B_ * 16, 512, 0, stream>>>(features, fps_idx, nbr);
  gather_kernel<<<B_ * M_ / 2, 256, 0, stream>>>(h, stats, nbr, out);
  tail_kernel<<<256, 256, 0, stream>>>(positions, fps_idx, out, batch_as_i64);
}

// Round 4
// 1020.632 us; speedup vs baseline: 1.4185x; 1.1406x over previous
//
#include <hip/hip_runtime.h>

#define B_ 16
#define N_ 4096
#define CIN_ 64
#define COUT_ 128
#define K_ 16
#define M_ 1024

typedef float f32x2 __attribute__((ext_vector_type(2)));
typedef unsigned long long u64;

#define DPPF(m, ctrl)                                                          \
  m = fmaxf(m, __int_as_float(__builtin_amdgcn_update_dpp(                     \
                  0, __float_as_int(m), ctrl, 0xF, 0xF, true)))
#define DPPI(e, ctrl)                                                          \
  e = max(e, __builtin_amdgcn_update_dpp(0, e, ctrl, 0xF, 0xF, true))

__device__ __forceinline__ unsigned mono32(float d) {
  unsigned u = __float_as_uint(d);
  return u ^ (unsigned)(((int)u >> 31) | 0x80000000);
}

// Mega kernel: blocks [0,16) = FPS (one per batch, publishes prog[b] every 64
// steps, agent-release). Blocks [16, 16+256*S) = kNN split blocks (qt-major
// ordering so dispatch order matches release order; acquire-spin on prog).
// Blocks [16+256*S, +512) = linear + BN-stats partials.
// 84 KB shared char buffer reinterpreted per role -> 1 block/CU.
__global__ __launch_bounds__(512) void mega_kernel(
    const float* __restrict__ pos, const float* __restrict__ features,
    const float* __restrict__ W, const float* __restrict__ bias,
    int* __restrict__ fps_idx, float* __restrict__ h,
    float* __restrict__ stats, int* __restrict__ prog,
    u64* __restrict__ cand, int S) {
  __shared__ __align__(16) char smem[84 * 1024];
  const int id = blockIdx.x;
  const int t = threadIdx.x;

  if (id < B_) {
    // ------------------------- FPS -------------------------
    const int b = id;
    float4* P = (float4*)smem;  // 64 KB
    u64* red = (u64*)(smem + 65536);  // [2][4]
    const float* pb = pos + (size_t)b * N_ * 3;
    for (int i = t; i < N_; i += 512)
      P[i] = make_float4(pb[i * 3], pb[i * 3 + 1], pb[i * 3 + 2], 0.f);
    __syncthreads();
    if (t < 256) {
      f32x2 px[8], py[8], pz[8], md[8];
#pragma unroll
      for (int j = 0; j < 8; ++j) {
        const float4 lo = P[t + 512 * j];
        const float4 hi = P[t + 512 * j + 256];
        px[j] = (f32x2){lo.x, hi.x};
        py[j] = (f32x2){lo.y, hi.y};
        pz[j] = (f32x2){lo.z, hi.z};
        md[j] = (f32x2){1e10f, 1e10f};
      }
      if (t == 0) fps_idx[b * M_] = 0;
      const int wv = t >> 6, ln = t & 63;
      const int e0 = 65535 - t;
      float4 lp = P[0];
      for (int step = 1; step < M_; ++step) {
        const f32x2 lx = {lp.x, lp.x}, ly = {lp.y, lp.y}, lz = {lp.z, lp.z};
        float bestd = -1.0f;
        int be = 0;
        {
#pragma clang fp contract(off)
#pragma unroll
          for (int j = 0; j < 8; ++j) {
            const f32x2 dx = px[j] - lx;
            const f32x2 dy = py[j] - ly;
            const f32x2 dz = pz[j] - lz;
            const f32x2 s1 = dx * dx;
            const f32x2 s2 = dy * dy;
            const f32x2 s3 = dz * dz;
            const f32x2 d = (s1 + s2) + s3;  // exact reference order
            f32x2 nd;
            nd.x = fminf(md[j].x, d.x);
            nd.y = fminf(md[j].y, d.y);
            md[j] = nd;
            if (nd.x > bestd) { bestd = nd.x; be = e0 - (j << 9); }
            if (nd.y > bestd) { bestd = nd.y; be = e0 - (j << 9) - 256; }
          }
        }
        float m = bestd;
        DPPF(m, 0x111); DPPF(m, 0x112); DPPF(m, 0x114); DPPF(m, 0x118);
        DPPF(m, 0x142); DPPF(m, 0x143);
        const float wm =
            __int_as_float(__builtin_amdgcn_readlane(__float_as_int(m), 63));
        int enc = (bestd == wm) ? be : 0;
        DPPI(enc, 0x111); DPPI(enc, 0x112); DPPI(enc, 0x114); DPPI(enc, 0x118);
        DPPI(enc, 0x142); DPPI(enc, 0x143);
        const int wenc = __builtin_amdgcn_readlane(enc, 63);
        if (ln == 0)
          red[(step & 1) * 4 + wv] =
              ((u64)__float_as_uint(wm) << 32) | (unsigned)wenc;
        __syncthreads();
        const u64* rb = &red[(step & 1) * 4];
        u64 rr = rb[0] > rb[1] ? rb[0] : rb[1];
        const u64 r2 = rb[2] > rb[3] ? rb[2] : rb[3];
        if (r2 > rr) rr = r2;
        const int last = 65535 - (int)(unsigned)(rr & 0xFFFFFFFFu);
        lp = P[last];
        if (t == 0) {
          fps_idx[b * M_ + step] = last;
          if ((step & 63) == 63)
            __hip_atomic_store(&prog[b], (step >> 6) + 1, __ATOMIC_RELEASE,
                               __HIP_MEMORY_SCOPE_AGENT);
        }
      }
    } else {
      for (int step = 1; step < M_; ++step) __syncthreads();
    }
    return;
  }

  if (id < B_ + 256 * S) {
    // ------------------------- kNN split block -------------------------
    const int kid = id - B_;
    const int qt = kid / (B_ * S);
    const int rem = kid % (B_ * S);
    const int b = rem / S;
    const int s = rem % S;
    const int KPS = N_ / S;    // keys per split
    const int KT = KPS / 128;  // 128-key tiles
    float* Qs = (float*)smem;                     // 16 KB
    float* Ks = (float*)(smem + 16384);           // 32 KB
    float* sd2 = (float*)(smem + 49152);          // 64*132*4
    float* qq = (float*)(smem + 82944);           // 256 B
    float* ff = (float*)(smem + 83200);           // 512 B
    int* qid = (int*)(smem + 83712);              // 256 B
    const float* fb = features + (size_t)b * N_ * CIN_;

    if (t == 0) {
      while (__hip_atomic_load(&prog[b], __ATOMIC_ACQUIRE,
                               __HIP_MEMORY_SCOPE_AGENT) < qt + 1)
        __builtin_amdgcn_s_sleep(16);
    }
    __syncthreads();
    if (t < 64) qid[t] = fps_idx[b * M_ + qt * 64 + t];
    __syncthreads();
#pragma unroll
    for (int st = 0; st < 2; ++st) {
      const int iid = t + 512 * st;
      const int row = iid >> 4, c4 = iid & 15;
      const int pc = (c4 + (row >> 2)) & 15;
      const float4 v = *(const float4*)(fb + (size_t)qid[row] * CIN_ + c4 * 4);
      *(float4*)(&Qs[row * 64 + pc * 4]) = v;
    }
    __syncthreads();
    if (t < 64) {
      float sv = 0.f;
#pragma unroll
      for (int c4 = 0; c4 < 16; ++c4) {
        const int pc = (c4 + (t >> 2)) & 15;
        const float4 v = *(const float4*)(&Qs[t * 64 + pc * 4]);
        sv = fmaf(v.x, v.x, sv); sv = fmaf(v.y, v.y, sv);
        sv = fmaf(v.z, v.z, sv); sv = fmaf(v.w, v.w, sv);
      }
      qq[t] = sv;
    }

    u64 lst[16];
#pragma unroll
    for (int p = 0; p < 16; ++p) lst[p] = ~0ull;
    u64 worst = ~0ull;
    int wpos = 0;

    const int q0 = (t >> 5) * 4;
    const int k0 = (t & 31) * 4;
    const int sq = t >> 3;
    const int ssub = t & 7;

    for (int kt = 0; kt < KT; ++kt) {
      const int kb = s * KPS + kt * 128;
#pragma unroll
      for (int st = 0; st < 4; ++st) {
        const int iid = t + 512 * st;
        const int row = iid >> 4, c4 = iid & 15;
        const int pc = (c4 + (row >> 2)) & 15;
        const float4 v = *(const float4*)(fb + (size_t)(kb + row) * CIN_ + c4 * 4);
        *(float4*)(&Ks[row * 64 + pc * 4]) = v;
      }
      __syncthreads();
      if (t < 128) {
        float sv = 0.f;
#pragma unroll
        for (int c4 = 0; c4 < 16; ++c4) {
          const int pc = (c4 + (t >> 2)) & 15;
          const float4 v = *(const float4*)(&Ks[t * 64 + pc * 4]);
          sv = fmaf(v.x, v.x, sv); sv = fmaf(v.y, v.y, sv);
          sv = fmaf(v.z, v.z, sv); sv = fmaf(v.w, v.w, sv);
        }
        ff[t] = sv;
      }
      __syncthreads();
      float acc[4][4];
#pragma unroll
      for (int i = 0; i < 4; ++i)
#pragma unroll
        for (int j = 0; j < 4; ++j) acc[i][j] = 0.f;
#pragma unroll
      for (int c4 = 0; c4 < 16; ++c4) {
        float4 qv[4], kv[4];
#pragma unroll
        for (int i = 0; i < 4; ++i) {
          const int row = q0 + i;
          const int pc = (c4 + (row >> 2)) & 15;
          qv[i] = *(const float4*)(&Qs[row * 64 + pc * 4]);
        }
#pragma unroll
        for (int j = 0; j < 4; ++j) {
          const int row = k0 + j;
          const int pc = (c4 + (row >> 2)) & 15;
          kv[j] = *(const float4*)(&Ks[row * 64 + pc * 4]);
        }
#pragma unroll
        for (int i = 0; i < 4; ++i)
#pragma unroll
          for (int j = 0; j < 4; ++j) {
            acc[i][j] = fmaf(qv[i].x, kv[j].x, acc[i][j]);
            acc[i][j] = fmaf(qv[i].y, kv[j].y, acc[i][j]);
            acc[i][j] = fmaf(qv[i].z, kv[j].z, acc[i][j]);
            acc[i][j] = fmaf(qv[i].w, kv[j].w, acc[i][j]);
          }
      }
#pragma unroll
      for (int i = 0; i < 4; ++i) {
        const float qv = qq[q0 + i];
        float4 o;
        o.x = __fsub_rn(__fadd_rn(qv, ff[k0 + 0]), 2.f * acc[i][0]);
        o.y = __fsub_rn(__fadd_rn(qv, ff[k0 + 1]), 2.f * acc[i][1]);
        o.z = __fsub_rn(__fadd_rn(qv, ff[k0 + 2]), 2.f * acc[i][2]);
        o.w = __fsub_rn(__fadd_rn(qv, ff[k0 + 3]), 2.f * acc[i][3]);
        *(float4*)(&sd2[(q0 + i) * 132 + k0]) = o;
      }
      __syncthreads();
#pragma unroll
      for (int g = 0; g < 4; ++g) {
        const float4 v = *(const float4*)(&sd2[sq * 132 + ssub * 16 + g * 4]);
        const float dv[4] = {v.x, v.y, v.z, v.w};
#pragma unroll
        for (int jj = 0; jj < 4; ++jj) {
          const int key = kb + ssub * 16 + g * 4 + jj;
          const u64 pk = ((u64)mono32(dv[jj]) << 32) | (unsigned)key;
          if (pk < worst) {
#pragma unroll
            for (int p = 0; p < 16; ++p)
              if (p == wpos) lst[p] = pk;
            worst = lst[0]; wpos = 0;
#pragma unroll
            for (int p = 1; p < 16; ++p)
              if (lst[p] > worst) { worst = lst[p]; wpos = p; }
          }
        }
      }
      __syncthreads();
    }
    // per-(query, split) sorted top-16 -> cand[q][s][0..15]
    u64* cb = cand + ((size_t)(b * M_ + qt * 64 + sq) * S + s) * 16;
    for (int r = 0; r < K_; ++r) {
      u64 mn = lst[0];
#pragma unroll
      for (int p = 1; p < 16; ++p)
        if (lst[p] < mn) mn = lst[p];
      u64 m2 = mn;
#pragma unroll
      for (int off = 1; off < 8; off <<= 1) {
        const u64 o = __shfl_xor(m2, off, 64);
        if (o < m2) m2 = o;
      }
      if (mn == m2) {
        bool done = false;
#pragma unroll
        for (int p = 0; p < 16; ++p)
          if (!done && lst[p] == m2) { lst[p] = ~0ull; done = true; }
      }
      if (ssub == 0) cb[r] = m2;
    }
    return;
  }

  // ------------------------- linear + stats partials -------------------------
  const int lid = id - (B_ + 256 * S);  // 0..511, 128 rows each
  float* ls = (float*)smem;             // 256 floats
  for (int i = t; i < 256; i += 512) ls[i] = 0.f;
  __syncthreads();
  const int o4 = (t & 31) << 2;
  const int rl = t >> 5;  // 0..15
  const float4 bv = *(const float4*)(bias + o4);
  float4 s4 = {0, 0, 0, 0}, ss4 = {0, 0, 0, 0};
  for (int i = 0; i < 8; ++i) {
    const int r = lid * 128 + rl * 8 + i;
    const float4* fr = (const float4*)(features + (size_t)r * CIN_);
    float4 acc = bv;
#pragma unroll
    for (int c4 = 0; c4 < 16; ++c4) {
      const float4 fv = fr[c4];
      const float* wr = W + (size_t)(c4 * 4) * COUT_ + o4;
      const float4 w0 = *(const float4*)(wr);
      const float4 w1 = *(const float4*)(wr + COUT_);
      const float4 w2 = *(const float4*)(wr + 2 * COUT_);
      const float4 w3 = *(const float4*)(wr + 3 * COUT_);
      acc.x = fmaf(fv.x, w0.x, acc.x); acc.y = fmaf(fv.x, w0.y, acc.y);
      acc.z = fmaf(fv.x, w0.z, acc.z); acc.w = fmaf(fv.x, w0.w, acc.w);
      acc.x = fmaf(fv.y, w1.x, acc.x); acc.y = fmaf(fv.y, w1.y, acc.y);
      acc.z = fmaf(fv.y, w1.z, acc.z); acc.w = fmaf(fv.y, w1.w, acc.w);
      acc.x = fmaf(fv.z, w2.x, acc.x); acc.y = fmaf(fv.z, w2.y, acc.y);
      acc.z = fmaf(fv.z, w2.z, acc.z); acc.w = fmaf(fv.z, w2.w, acc.w);
      acc.x = fmaf(fv.w, w3.x, acc.x); acc.y = fmaf(fv.w, w3.y, acc.y);
      acc.z = fmaf(fv.w, w3.z, acc.z); acc.w = fmaf(fv.w, w3.w, acc.w);
    }
    *(float4*)(h + (size_t)r * COUT_ + o4) = acc;
    s4.x += acc.x; s4.y += acc.y; s4.z += acc.z; s4.w += acc.w;
    ss4.x = fmaf(acc.x, acc.x, ss4.x); ss4.y = fmaf(acc.y, acc.y, ss4.y);
    ss4.z = fmaf(acc.z, acc.z, ss4.z); ss4.w = fmaf(acc.w, acc.w, ss4.w);
  }
  atomicAdd(&ls[o4 + 0], s4.x); atomicAdd(&ls[o4 + 1], s4.y);
  atomicAdd(&ls[o4 + 2], s4.z); atomicAdd(&ls[o4 + 3], s4.w);
  atomicAdd(&ls[128 + o4 + 0], ss4.x); atomicAdd(&ls[128 + o4 + 1], ss4.y);
  atomicAdd(&ls[128 + o4 + 2], ss4.z); atomicAdd(&ls[128 + o4 + 3], ss4.w);
  __syncthreads();
  if (t < 128) {
    atomicAdd(&stats[t], ls[t]);
    atomicAdd(&stats[128 + t], ls[128 + t]);
  }
}

__global__ void finalize_kernel(float* __restrict__ stats,
                                const float* __restrict__ gamma,
                                const float* __restrict__ beta) {
  const int o = threadIdx.x;  // 128
  const float inv = 1.0f / (float)(B_ * N_);
  const float mean = stats[o] * inv;
  const float var = stats[128 + o] * inv - mean * mean;
  const float r = 1.0f / sqrtf(var + 1e-5f);
  const float sc = gamma[o] * r;
  stats[256 + o] = sc;
  stats[384 + o] = beta[o] - mean * sc;
}

// Merge S sorted per-split lists (exact u64 lexicographic order) + gather +
// BN + maxpool. 2 queries x 128 channels per block.
__global__ __launch_bounds__(256) void gather_kernel(
    const float* __restrict__ h, const float* __restrict__ stats,
    const u64* __restrict__ cand, float* __restrict__ out, int S) {
  const int g = blockIdx.x;
  const int t = threadIdx.x;
  const int S16 = S * 16;
  __shared__ u64 cl[2][128];
  __shared__ int nbi[32];
  const int Q0 = g * 2;
  if (t < 2 * S16) {
    const int qi = t / S16, sl = t % S16;
    cl[qi][sl] = cand[(size_t)(Q0 + qi) * S16 + sl];
  }
  __syncthreads();
  if ((t & 127) == 0) {
    const int qi = t >> 7;
    int ptr[8] = {0, 0, 0, 0, 0, 0, 0, 0};
    for (int r = 0; r < K_; ++r) {
      u64 mn = ~0ull;
      int ms = 0;
      for (int s = 0; s < S; ++s) {
        if (ptr[s] < 16) {
          const u64 v = cl[qi][s * 16 + ptr[s]];
          if (v < mn) { mn = v; ms = s; }
        }
      }
      nbi[qi * 16 + r] = (int)(unsigned)(mn & 0xFFFFFFFFu);
      ptr[ms]++;
    }
  }
  __syncthreads();
  const int q2 = t >> 7, o = t & 127;
  const int Q = Q0 + q2, b = Q >> 10;
  const float sc = stats[256 + o];
  const float sh = stats[384 + o];
  float mx = -3.402823466e38f;
#pragma unroll
  for (int k = 0; k < K_; ++k) {
    const int n = nbi[q2 * 16 + k];
    const float v = fmaf(h[((size_t)b * N_ + n) * COUT_ + o], sc, sh);
    mx = fmaxf(mx, v);
  }
  out[(size_t)Q * COUT_ + o] = mx;
}

__global__ __launch_bounds__(256) void tail_kernel(const float* __restrict__ pos,
                                                   const int* __restrict__ fps_idx,
                                                   float* __restrict__ out,
                                                   int batch_as_i64) {
  const int gid = blockIdx.x * 256 + threadIdx.x;
  const int A = B_ * M_ * COUT_;
  const int P = B_ * M_ * 3;
  if (gid < P) {
    const int Q = gid / 3;
    const int c = gid - Q * 3;
    const int b = Q >> 10;
    const int idx = fps_idx[Q];
    out[A + gid] = pos[((size_t)b * N_ + idx) * 3 + c];
  } else {
    const int Q = gid - P;
    if (Q < B_ * M_) {
      const int b = Q >> 10;
      float* base = out + A + P;
      if (batch_as_i64)
        ((long long*)base)[Q] = (long long)b;
      else
        base[Q] = (float)b;
    }
  }
}

extern "C" void kernel_launch(void* const* d_in, const int* in_sizes, int n_in,
                              void* d_out, int out_size, void* d_ws, size_t ws_size,
                              hipStream_t stream) {
  const float* features = (const float*)d_in[0];
  const float* positions = (const float*)d_in[1];
  const float* W = (const float*)d_in[3];
  const float* bias = (const float*)d_in[4];
  const float* gamma = (const float*)d_in[5];
  const float* beta = (const float*)d_in[6];
  float* out = (float*)d_out;
  unsigned char* ws = (unsigned char*)d_ws;

  int* fps_idx = (int*)ws;                                // 64 KB
  float* h = (float*)(ws + 65536);                        // 33.5 MB
  const size_t hoff = 65536 + (size_t)B_ * N_ * COUT_ * 4;
  float* stats = (float*)(ws + hoff);                     // 2 KB
  int* prog = (int*)(ws + hoff + 2048);                   // 256 B
  u64* cand = (u64*)(ws + hoff + 2048 + 256);
  const size_t base = hoff + 2048 + 256;

  int S = 8;  // key-split factor; shrink if workspace is small
  while (S > 1 && base + (size_t)B_ * M_ * S * 16 * 8 > ws_size) S >>= 1;

  const int rem = out_size - (B_ * M_ * COUT_) - (B_ * M_ * 3);
  const int batch_as_i64 = (rem >= 2 * B_ * M_) ? 1 : 0;

  hipMemsetAsync(stats, 0, 2048 + 256, stream);  // stats + prog
  mega_kernel<<<B_ + 256 * S + 512, 512, 0, stream>>>(
      positions, features, W, bias, fps_idx, h, stats, prog, cand, S);
  finalize_kernel<<<1, 128, 0, stream>>>(stats, gamma, beta);
  gather_kernel<<<B_ * M_ / 2, 256, 0, stream>>>(h, stats, cand, out, S);
  tail_kernel<<<256, 256, 0, stream>>>(positions, fps_idx, out, batch_as_i64);
}